// Round 10
// baseline (297.965 us; speedup 1.0000x reference)
//
#include <hip/hip_runtime.h>

#define BB    8
#define LQN   2048
#define LKVN  2048
#define DQ    128
#define DVN   128
#define QT    16            // Q rows per block
#define KTI   128           // KV per staged tile (4 waves x 32)
#define NT    (LKVN / KTI)  // 16 tiles
#define OSTR  132           // osum row stride (f32)

typedef short short8 __attribute__((ext_vector_type(8)));
typedef float f32x4  __attribute__((ext_vector_type(4)));
typedef int   int4v  __attribute__((ext_vector_type(4)));

__device__ __forceinline__ short f2bf(float f) {
  unsigned u = __builtin_bit_cast(unsigned, f);
  u += 0x7fffu + ((u >> 16) & 1u);   // round-to-nearest-even
  return (short)(u >> 16);
}

__device__ __forceinline__ int packbf(float a, float b) {
  unsigned lo = (unsigned short)f2bf(a);
  unsigned hi = (unsigned short)f2bf(b);
  return (int)(lo | (hi << 16));
}

// Fused preprocessing, one launch:
//   blocks [0,512):    V (B,LKV,DV) fp32 -> Vt (B,DV,LKV) bf16
//   blocks [512,1536): K fp32 -> bf16 flat copy
__global__ __launch_bounds__(256) void pre_kernel(const float* __restrict__ K,
                                                  const float* __restrict__ V,
                                                  short* __restrict__ Kb,
                                                  short* __restrict__ Vt) {
  __shared__ float tile[128][33];
  if (blockIdx.x >= 512) {
    int i = (blockIdx.x - 512) * 256 + threadIdx.x;   // 262144 threads x 8 elems
    size_t off = (size_t)i * 8;
    float4 a = *(const float4*)(K + off);
    float4 c = *(const float4*)(K + off + 4);
    short8 o;
    o[0] = f2bf(a.x); o[1] = f2bf(a.y); o[2] = f2bf(a.z); o[3] = f2bf(a.w);
    o[4] = f2bf(c.x); o[5] = f2bf(c.y); o[6] = f2bf(c.z); o[7] = f2bf(c.w);
    *(short8*)(Kb + off) = o;
    return;
  }
  const int bx  = blockIdx.x;
  const int kv0 = (bx & 15) * 128;
  const int dv0 = ((bx >> 4) & 3) * 32;
  const int b   = bx >> 6;
  const int tid = threadIdx.x;
  const float* src = V + ((size_t)b * LKVN + kv0) * DVN + dv0;
#pragma unroll
  for (int it = 0; it < 4; ++it) {
    int idx = it * 256 + tid;
    int r = idx >> 3, c4 = idx & 7;
    float4 v = *(const float4*)(src + (size_t)r * DVN + c4 * 4);
    tile[r][c4 * 4 + 0] = v.x;
    tile[r][c4 * 4 + 1] = v.y;
    tile[r][c4 * 4 + 2] = v.z;
    tile[r][c4 * 4 + 3] = v.w;
  }
  __syncthreads();
  short* dst = Vt + ((size_t)b * DVN + dv0) * LKVN + kv0;
#pragma unroll
  for (int it = 0; it < 2; ++it) {
    int idx = it * 256 + tid;
    int row = idx >> 4, ch = idx & 15;
    short8 o;
#pragma unroll
    for (int j = 0; j < 8; ++j) o[j] = f2bf(tile[ch * 8 + j][row]);
    *(short8*)(dst + (size_t)row * LKVN + ch * 8) = o;
  }
}

// 4-wave two-sweep attention: R8's verified math on R0's geometry.
// QT=16, grid 1024 -> FOUR independent barrier groups per CU (R0's champion
// feature; R7/R8's 8-wave blocks gave only 2-3 and lost to R0). Wave w owns kv
// slice [w*32, w*32+32) of each 128-kv tile. Single 32 KB swizzled k_lds,
// R0's 2-barrier reg-prefetch staging (kreg dies at ds_write -> allocator
// can't collapse the prefetch). V direct from L2 (R8 pattern). Swapped MFMA
// S^T = mfma(K,Q); shfl P-exchange (bpermute = 2cy each, measured R8->R9);
// k=32 PV (R9's k=16 regressed 56us - reverted); float4 W stores.
// amdgpu_waves_per_eu(4,4): pins occupancy at 16 waves/CU (= our 4 blocks x
// 4 waves) and raises the VGPR budget to 512/4 = 128 — the allocator pinned
// 64 VGPRs in ALL nine prior rounds and sank prefetch loads; P2's ~119-reg
// live set now fits the cap.
// K staging map: thread t stages 8 chunks j: row = j*16 + (t>>4), granule
// t&15, source granule pre-swizzled ^(row&7) (m173). ds_writes are linear
// 1KB/wave per j (conflict-free); reads use the verified R8 swizzle.
__global__ __launch_bounds__(256)
__attribute__((amdgpu_waves_per_eu(4, 4)))
void attn_kernel(const float* __restrict__ Q,
                 const short* __restrict__ Kb,
                 const short* __restrict__ Vt,
                 float* __restrict__ W,
                 float* __restrict__ O) {
  __shared__ __align__(16) short k_lds[KTI * 128];      // 32 KB, swizzled
  __shared__ float red_l[4][QT];
  float (*osum)[QT][OSTR] = (float (*)[QT][OSTR])k_lds; // epilogue alias (16.9KB)

  const int tid  = threadIdx.x;
  const int w    = tid >> 6;                 // 0..3: kv slice
  const int lane = tid & 63;
  const int n    = lane & 15;
  const int qd   = lane >> 4;
  const int b    = blockIdx.x & 7;           // batch -> XCD
  const int q0   = (blockIdx.x >> 3) * QT;

  const short* Kbase = Kb + (size_t)b * LKVN * DQ;
  const short* Vw = Vt + ((size_t)b * DVN + n) * LKVN + w * 32 + qd * 8;
  float* Wrow = W + ((size_t)b * LQN + q0 + n) * LKVN + w * 32 + qd * 4;

  // K staging indices (fixed per thread)
  const int srow  = tid >> 4;                        // 0..15
  const int scol8 = (tid & 15) * 8;                  // LDS granule (shorts)
  const int gsrc8 = ((tid & 15) ^ (srow & 7)) * 8;   // pre-swizzled source

  // MFMA-read base: row = w*32 + t2*16 + n, col = (ks*32+qd*8) ^ ((n&7)*8)
  const int krow = (w * 32 + n) * 128;
  const int rswz = (n & 7) << 3;

  // Q B-fragments straight from fp32 (per-block one-shot)
  short8 qf[4];
  {
    const float* Qrow = Q + ((size_t)b * LQN + q0 + n) * DQ + qd * 8;
#pragma unroll
    for (int ks = 0; ks < 4; ++ks) {
      float4 f0 = *(const float4*)(Qrow + ks * 32);
      float4 f1 = *(const float4*)(Qrow + ks * 32 + 4);
      short8 o;
      o[0] = f2bf(f0.x); o[1] = f2bf(f0.y); o[2] = f2bf(f0.z); o[3] = f2bf(f0.w);
      o[4] = f2bf(f1.x); o[5] = f2bf(f1.y); o[6] = f2bf(f1.z); o[7] = f2bf(f1.w);
      qf[ks] = o;
    }
  }

  const float scale = 0.08838834764831845f;  // 1/sqrt(128)
  float l_part = 0.f;
  short8 kreg[8];

#define KLOAD(t)                                                                \
  _Pragma("unroll")                                                             \
  for (int j = 0; j < 8; ++j)                                                   \
    kreg[j] = *(const short8*)(Kbase + (size_t)((t) * KTI + j * 16 + srow) * DQ + gsrc8);
#define KWRITE()                                                                \
  _Pragma("unroll")                                                             \
  for (int j = 0; j < 8; ++j)                                                   \
    *(short8*)&k_lds[(j * 16 + srow) * 128 + scol8] = kreg[j];

  // ---------------- phase 1: per-q row sums of exp(s) ----------------
  KLOAD(0)
  KWRITE()
  for (int t = 0; t < NT; ++t) {
    __syncthreads();                       // A: staged tile visible
    if (t + 1 < NT) KLOAD(t + 1)           // prefetch next tile into regs
#pragma unroll
    for (int t2 = 0; t2 < 2; ++t2) {
      f32x4 acc = {0.f, 0.f, 0.f, 0.f};
#pragma unroll
      for (int ks = 0; ks < 4; ++ks) {
        short8 kf = *(const short8*)&k_lds[krow + t2 * 2048 + ((ks * 32 + qd * 8) ^ rswz)];
        acc = __builtin_amdgcn_mfma_f32_16x16x32_bf16(kf, qf[ks], acc, 0, 0, 0);
      }
#pragma unroll
      for (int r = 0; r < 4; ++r) l_part += __expf(acc[r] * scale);
    }
    __syncthreads();                       // C: all waves done reading
    if (t + 1 < NT) KWRITE()
  }

  // reduce l over qd groups (same q lives in lanes n, n+16, n+32, n+48)
  l_part += __shfl_xor(l_part, 16, 64);
  l_part += __shfl_xor(l_part, 32, 64);
  if (lane < 16) red_l[w][lane] = l_part;
  KLOAD(0)                                 // restage tile 0 under the reduce
  __syncthreads();
  const float rinv = 1.0f / (red_l[0][n] + red_l[1][n] + red_l[2][n] + red_l[3][n]);
  KWRITE()

  // ---------------- phase 2: W write + PV ----------------
  const int srcA = n + ((qd & 1) << 5);   // lane holding kv sub-block 2*(qd&1)
  const int srcB = srcA + 16;             // lane holding kv sub-block 2*(qd&1)+1
  const int sel  = qd >> 1;               // which 16-kv half (t2) this lane consumes

  f32x4 oacc[8];
#pragma unroll
  for (int dvg = 0; dvg < 8; ++dvg) oacc[dvg] = (f32x4){0.f, 0.f, 0.f, 0.f};

  for (int t = 0; t < NT; ++t) {
    __syncthreads();                       // A: k_lds[t] visible
    f32x4 acc[2];
    __builtin_amdgcn_s_setprio(1);
#pragma unroll
    for (int t2 = 0; t2 < 2; ++t2) {
      acc[t2] = (f32x4){0.f, 0.f, 0.f, 0.f};
#pragma unroll
      for (int ks = 0; ks < 4; ++ks) {
        short8 kf = *(const short8*)&k_lds[krow + t2 * 2048 + ((ks * 32 + qd * 8) ^ rswz)];
        acc[t2] = __builtin_amdgcn_mfma_f32_16x16x32_bf16(kf, qf[ks], acc[t2], 0, 0, 0);
      }
    }
    __builtin_amdgcn_s_setprio(0);

    // V loads for the CURRENT tile (needed first) then K prefetch for t+1
    short8 vf[8];
#pragma unroll
    for (int dvg = 0; dvg < 8; ++dvg)
      vf[dvg] = *(const short8*)(Vw + (size_t)(dvg * 16) * LKVN + t * KTI);
    if (t + 1 < NT) KLOAD(t + 1)

    int pk[2][2];
#pragma unroll
    for (int t2 = 0; t2 < 2; ++t2) {
      float p0 = __expf(acc[t2][0] * scale) * rinv;
      float p1 = __expf(acc[t2][1] * scale) * rinv;
      float p2 = __expf(acc[t2][2] * scale) * rinv;
      float p3 = __expf(acc[t2][3] * scale) * rinv;
      f32x4 st = {p0, p1, p2, p3};
      *(f32x4*)(Wrow + t * KTI + t2 * 16) = st;
      pk[t2][0] = packbf(p0, p1);
      pk[t2][1] = packbf(p2, p3);
    }
    int a0 = __shfl(pk[0][0], srcA, 64);
    int b0 = __shfl(pk[1][0], srcA, 64);
    int a1 = __shfl(pk[0][1], srcA, 64);
    int b1 = __shfl(pk[1][1], srcA, 64);
    int a2 = __shfl(pk[0][0], srcB, 64);
    int b2 = __shfl(pk[1][0], srcB, 64);
    int a3 = __shfl(pk[0][1], srcB, 64);
    int b3 = __shfl(pk[1][1], srcB, 64);
    int4v bi;
    bi[0] = sel ? b0 : a0;
    bi[1] = sel ? b1 : a1;
    bi[2] = sel ? b2 : a2;
    bi[3] = sel ? b3 : a3;
    short8 bfr = __builtin_bit_cast(short8, bi);

    __builtin_amdgcn_s_setprio(1);
#pragma unroll
    for (int dvg = 0; dvg < 8; ++dvg)
      oacc[dvg] = __builtin_amdgcn_mfma_f32_16x16x32_bf16(vf[dvg], bfr, oacc[dvg], 0, 0, 0);
    __builtin_amdgcn_s_setprio(0);

    __syncthreads();                       // C: all k_lds readers done
    if (t + 1 < NT) KWRITE()
  }

  // ---------------- cross-wave O reduction (osum aliases k_lds; all k_lds
  // readers are past the final barrier C, so the alias is safe) -------------
  if (w < 2) {
#pragma unroll
    for (int dvg = 0; dvg < 8; ++dvg)
      *(f32x4*)&osum[w][n][dvg * 16 + qd * 4] = oacc[dvg];
  }
  __syncthreads();
  if (w >= 2) {
#pragma unroll
    for (int dvg = 0; dvg < 8; ++dvg) {
      f32x4* p = (f32x4*)&osum[w - 2][n][dvg * 16 + qd * 4];
      *p = *p + oacc[dvg];
    }
  }
  __syncthreads();

  float* Ob = O + ((size_t)b * LQN + q0) * DVN;
  const int qq = tid >> 4;        // 16 q rows, 16 threads each
  const int c0 = (tid & 15) * 8;  // 8 dv per thread
#pragma unroll
  for (int c = 0; c < 2; ++c) {
    f32x4 s0 = *(const f32x4*)&osum[0][qq][c0 + c * 4];
    f32x4 s1 = *(const f32x4*)&osum[1][qq][c0 + c * 4];
    s0 = s0 + s1;
    *(f32x4*)(Ob + (size_t)qq * DVN + c0 + c * 4) = s0;
  }
}

extern "C" void kernel_launch(void* const* d_in, const int* in_sizes, int n_in,
                              void* d_out, int out_size, void* d_ws, size_t ws_size,
                              hipStream_t stream) {
  const float* Q = (const float*)d_in[0];
  const float* K = (const float*)d_in[1];
  const float* V = (const float*)d_in[2];
  float* W = (float*)d_out;                        // (B, LQ, LKV)
  float* O = W + (size_t)BB * LQN * LKVN;          // (B, LQ, DV)
  short* Kb = (short*)d_ws;                        // 4 MB bf16 (B, LKV, D)
  short* Vt = Kb + (size_t)BB * LKVN * DQ;         // 4 MB bf16 (B, DV, LKV)

  pre_kernel<<<1536, 256, 0, stream>>>(K, V, Kb, Vt);
  attn_kernel<<<1024, 256, 0, stream>>>(Q, Kb, Vt, W, O);
}